// Round 6
// baseline (375.031 us; speedup 1.0000x reference)
//
#include <hip/hip_runtime.h>
#include <hip/hip_bf16.h>

// Flash attention fwd, 1 head, B=64, S=1024, D=256.
// Inputs/outputs fp32 (per reference); compute in bf16 MFMA, fp32 accum.
// Dual-dtype insurance kept as ONE kernel with a block-uniform branch.
//
// R5 (resubmit; previous run died to a container-infra failure, kernel
// statically re-audited: LDS 38400B x4 = 153600 <= 160K, all LDS indexing
// in-bounds, barriers block-uniform).
// Occupancy attack via LDS, not registers. R3 (204us) had no saturated
// pipe (DS ~40%, VALU 29%, MFMA 14%, HBM 22%) at 8 waves/CU -> latency/
// barrier-stall bound. R4's fix (bigger per-wave tile) blew the 128-VGPR
// tier and spilled. R5 keeps R3's per-wave geometry EXACTLY (16 q-rows,
// 124 VGPR) and shrinks the KV tile: BK=32 -> LDS 38.4KB -> 4 blocks/CU
// -> 16 waves/CU (~44-50% occupancy), 2x R3's TLP. Same total work per
// output; only barriers double, amortized across 4 interleaved blocks.
//  - grid (batch, qtile) kept from R4: FETCH 295->76MB verified.
//  - vs granule rotation for 4 granules/d: rot=((d>>3)+kc)&3, hand-checked
//    conflict-free for build writes and PV reads.
// Carried from R3: DPP softmax reductions, vs dword-pair build, defer-
// rescale, KPAD=264 staging/QK layout.

#define NB   64
#define NQ   1024
#define NKV  1024
#define DM   256
#define BQ   64     // q rows per block (4 waves x 16)
#define BK   32     // kv rows per tile
#define KPAD 264    // ks row stride (elems): 528B
#define PPAD 40     // ps row stride (elems): 80B, 16B-aligned
#define LOG2E   1.4426950408889634f
#define SCL     (0.0625f * LOG2E)   // fold scale=256^-0.5 into exp2 arg
#define NEG_BIG (-1e30f)            // finite "-inf"
#define THRU    30.0f               // defer threshold: P <= 2^(30*SCL) ~ 6.5

typedef __attribute__((ext_vector_type(8))) short  bf16x8;   // 8 bf16 = 4 VGPRs
typedef __attribute__((ext_vector_type(4))) float  floatx4;

__device__ __forceinline__ ushort f2bf(float f) {
  __hip_bfloat16 h = __float2bfloat16(f);
  return *(ushort*)&h;
}

// DPP lane-move within 16-lane rows (VALU pipe, no DS).
template <int CTRL>
__device__ __forceinline__ float dpp_mov(float x) {
  return __int_as_float(__builtin_amdgcn_update_dpp(
      0, __float_as_int(x), CTRL, 0xF, 0xF, false));
}
__device__ __forceinline__ float red16_max(float x) {
  x = fmaxf(x, dpp_mov<0xB1>(x));    // quad_perm xor1
  x = fmaxf(x, dpp_mov<0x4E>(x));    // quad_perm xor2
  x = fmaxf(x, dpp_mov<0x124>(x));   // row_ror:4
  x = fmaxf(x, dpp_mov<0x128>(x));   // row_ror:8
  return x;
}
__device__ __forceinline__ float red16_sum(float x) {
  x += dpp_mov<0xB1>(x);
  x += dpp_mov<0x4E>(x);
  x += dpp_mov<0x124>(x);
  x += dpp_mov<0x128>(x);
  return x;
}

// vs granule address (elems): granule = 8 consecutive kv of one d, kc=0..3.
// addr(d,kc) = (d>>3)*256 + (d&7)*32 + (((d>>3)+kc)&3)*8
__device__ __forceinline__ int vsoff(int d, int kc) {
  return ((d >> 3) << 8) + ((d & 7) << 5) + ((((d >> 3) + kc) & 3) << 3);
}

// flag=1: data is bf16; flag=0: data is fp32.
__global__ void detect_dtype(const unsigned int* __restrict__ q,
                             int* __restrict__ flag) {
  __shared__ int cnt;
  if (threadIdx.x == 0) cnt = 0;
  __syncthreads();
  unsigned int w = q[(size_t)threadIdx.x * 32003u];
  unsigned int e = (w >> 7) & 0xFFu;
  int good = (e >= 96u && e < 160u) ? 1 : 0;
  atomicAdd(&cnt, good);
  __syncthreads();
  if (threadIdx.x == 0) flag[0] = (cnt > 192) ? 1 : 0;
}

template <bool IS_BF16>
__device__ __forceinline__ void attn_body(
    const void* __restrict__ qv, const void* __restrict__ kvv,
    void* __restrict__ outv, ushort* ks, ushort* vs, ushort* ps)
{
  const int tid   = threadIdx.x;
  const int wave  = tid >> 6;
  const int lane  = tid & 63;
  const int quad  = lane >> 4;
  const int l16   = lane & 15;
  const int batch = blockIdx.x;       // id%8 == batch%8 -> same-XCD KV share
  const int q0    = blockIdx.y * BQ + wave * 16;

  // Q fragments, A-layout: a[j] = Q[m=l16][k = kb*32 + quad*8 + j]
  bf16x8 qf[8];
  if constexpr (IS_BF16) {
    const ushort* qp = (const ushort*)qv + ((size_t)(batch * NQ + q0 + l16)) * DM + quad * 8;
#pragma unroll
    for (int kb = 0; kb < 8; ++kb)
      qf[kb] = *(const bf16x8*)(qp + kb * 32);
  } else {
    const float* qp = (const float*)qv + ((size_t)(batch * NQ + q0 + l16)) * DM + quad * 8;
#pragma unroll
    for (int kb = 0; kb < 8; ++kb) {
      float4 f0 = *(const float4*)(qp + kb * 32);
      float4 f1 = *(const float4*)(qp + kb * 32 + 4);
      bf16x8 o; ushort* op = (ushort*)&o;
      op[0]=f2bf(f0.x); op[1]=f2bf(f0.y); op[2]=f2bf(f0.z); op[3]=f2bf(f0.w);
      op[4]=f2bf(f1.x); op[5]=f2bf(f1.y); op[6]=f2bf(f1.z); op[7]=f2bf(f1.w);
      qf[kb] = o;
    }
  }

  floatx4 acc[16];                // O acc: acc[nt][r] = O[quad*4+r][nt*16+l16]
#pragma unroll
  for (int i = 0; i < 16; ++i) acc[i] = (floatx4){0.f, 0.f, 0.f, 0.f};
  float m_i[4] = {NEG_BIG, NEG_BIG, NEG_BIG, NEG_BIG};   // UNSCALED running max
  float l_i[4] = {0.f, 0.f, 0.f, 0.f};

  // PV read bases (loop-invariant): d = nt*16 + l16
  const int hbase = ((l16 >> 3) << 8) + ((l16 & 7) << 5);
  const int hq    = (l16 >> 3) + quad;          // rot = ((nt<<1)+hq)&3

  ushort* pw = ps + wave * 16 * PPAD;

  for (int kt = 0; kt < NKV / BK; ++kt) {
    __syncthreads();  // protect ks/vs from previous iteration's readers
    // ---- stage kv tile 32x256 into LDS as bf16 (row-major, KPAD) ----
    if constexpr (IS_BF16) {
      const ushort* src = (const ushort*)kvv + ((size_t)batch * NKV + kt * BK) * DM;
#pragma unroll
      for (int i = 0; i < 4; ++i) {
        int v = tid + i * 256;      // 1024 vec8 chunks
        int r = v >> 5;             // 32 vec8 per row
        int c = (v & 31) << 3;
        *(bf16x8*)&ks[r * KPAD + c] = *(const bf16x8*)&src[r * DM + c];
      }
    } else {
      const float* src = (const float*)kvv + ((size_t)batch * NKV + kt * BK) * DM;
#pragma unroll
      for (int i = 0; i < 4; ++i) {
        int v = tid + i * 256;
        int r = v >> 5;
        int c = (v & 31) << 3;
        const float* sp = src + r * DM + c;
        float4 f0 = *(const float4*)(sp);
        float4 f1 = *(const float4*)(sp + 4);
        bf16x8 o; ushort* op = (ushort*)&o;
        op[0]=f2bf(f0.x); op[1]=f2bf(f0.y); op[2]=f2bf(f0.z); op[3]=f2bf(f0.w);
        op[4]=f2bf(f1.x); op[5]=f2bf(f1.y); op[6]=f2bf(f1.z); op[7]=f2bf(f1.w);
        *(bf16x8*)&ks[r * KPAD + c] = o;
      }
    }
    __syncthreads();

    // ---- S = Q @ K^T (unscaled) : 16x32 per wave ----
    floatx4 s[2];
#pragma unroll
    for (int nt = 0; nt < 2; ++nt) {
      floatx4 a = (floatx4){0.f, 0.f, 0.f, 0.f};
#pragma unroll
      for (int kb = 0; kb < 8; ++kb) {
        bf16x8 bfr = *(const bf16x8*)&ks[(nt * 16 + l16) * KPAD + kb * 32 + quad * 8];
        a = __builtin_amdgcn_mfma_f32_16x16x32_bf16(qf[kb], bfr, a, 0, 0, 0);
      }
      s[nt] = a;
    }

    // ---- build vs: thread owns d-pair (d0,d0+1) x 2 kv-octets ----
    // dword reads grab (d0,d0+1) of rows 528B apart; halves repacked in
    // VALU; b128 writes: 16 distinct bank slots per 16 lanes.
    {
      const int d0 = (tid & 127) << 1;
      const int o0 = tid >> 7;            // 0 or 1
      const int gb = ((d0 >> 3) << 8) + ((d0 & 7) << 5);
      const int r0 = d0 >> 3;
#pragma unroll
      for (int t = 0; t < 2; ++t) {
        const int oct = o0 + (t << 1);    // kv-octet 0..3
        const ushort* kp = ks + (oct << 3) * KPAD + d0;
        uint x0 = *(const uint*)(kp);
        uint y0 = *(const uint*)(kp + KPAD);
        uint x1 = *(const uint*)(kp + 2 * KPAD);
        uint y1 = *(const uint*)(kp + 3 * KPAD);
        uint x2 = *(const uint*)(kp + 4 * KPAD);
        uint y2 = *(const uint*)(kp + 5 * KPAD);
        uint x3 = *(const uint*)(kp + 6 * KPAD);
        uint y3 = *(const uint*)(kp + 7 * KPAD);
        uint4 glo, ghi;
        glo.x = (x0 & 0xFFFFu) | (y0 << 16);
        glo.y = (x1 & 0xFFFFu) | (y1 << 16);
        glo.z = (x2 & 0xFFFFu) | (y2 << 16);
        glo.w = (x3 & 0xFFFFu) | (y3 << 16);
        ghi.x = (x0 >> 16) | (y0 & 0xFFFF0000u);
        ghi.y = (x1 >> 16) | (y1 & 0xFFFF0000u);
        ghi.z = (x2 >> 16) | (y2 & 0xFFFF0000u);
        ghi.w = (x3 >> 16) | (y3 & 0xFFFF0000u);
        const int rot = (((r0 + oct) & 3) << 3);
        *(uint4*)&vs[gb + rot]      = glo;   // d0
        *(uint4*)&vs[gb + 32 + rot] = ghi;   // d0+1 (same d>>3, same rot)
      }
    }

    // ---- online softmax (DPP reductions, deferred rescale) ----
    float mx4[4];
#pragma unroll
    for (int r = 0; r < 4; ++r)
      mx4[r] = red16_max(fmaxf(s[0][r], s[1][r]));
    float grow = fmaxf(fmaxf(mx4[0] - m_i[0], mx4[1] - m_i[1]),
                       fmaxf(mx4[2] - m_i[2], mx4[3] - m_i[3]));
    if (__any(grow > THRU)) {
#pragma unroll
      for (int r = 0; r < 4; ++r) {
        float mnew  = fmaxf(m_i[r], mx4[r]);
        float alpha = exp2f(fmaxf((m_i[r] - mnew) * SCL, -126.f));
        l_i[r] *= alpha;
        m_i[r]  = mnew;
#pragma unroll
        for (int nt = 0; nt < 16; ++nt) acc[nt][r] *= alpha;
      }
    }
    float pv[2][4];  // [nt][r]
#pragma unroll
    for (int r = 0; r < 4; ++r) {
      float rs = 0.f;
#pragma unroll
      for (int nt = 0; nt < 2; ++nt) {
        float p = exp2f((s[nt][r] - m_i[r]) * SCL);
        pv[nt][r] = p;
        rs += p;
      }
      l_i[r] += red16_sum(rs);
    }

    // ---- P: C-layout regs -> LDS -> A-layout frag ----
#pragma unroll
    for (int nt = 0; nt < 2; ++nt)
#pragma unroll
      for (int r = 0; r < 4; ++r)
        pw[(quad * 4 + r) * PPAD + nt * 16 + l16] = f2bf(pv[nt][r]);
    __syncthreads();   // vs fully built by all waves (ps is wave-private)

    bf16x8 pf = *(const bf16x8*)&pw[l16 * PPAD + quad * 8];

    // ---- O += P @ V : b[j] = V[k=quad*8+j][n=nt*16+l16] via vs b128 ----
#pragma unroll
    for (int nt = 0; nt < 16; ++nt) {
      const int rot = (((nt << 1) + hq) & 3) << 3;
      bf16x8 vf = *(const bf16x8*)&vs[(nt << 9) + hbase + rot];
      acc[nt] = __builtin_amdgcn_mfma_f32_16x16x32_bf16(pf, vf, acc[nt], 0, 0, 0);
    }
  }

  // ---- epilogue: O / l, store in the REFERENCE dtype ----
#pragma unroll
  for (int r = 0; r < 4; ++r) l_i[r] = 1.f / l_i[r];
  if constexpr (IS_BF16) {
    ushort* ob = (ushort*)outv + ((size_t)(batch * NQ + q0 + quad * 4)) * DM + l16;
#pragma unroll
    for (int nt = 0; nt < 16; ++nt)
#pragma unroll
      for (int r = 0; r < 4; ++r)
        ob[(size_t)r * DM + nt * 16] = f2bf(acc[nt][r] * l_i[r]);
  } else {
    float* ob = (float*)outv + ((size_t)(batch * NQ + q0 + quad * 4)) * DM + l16;
#pragma unroll
    for (int nt = 0; nt < 16; ++nt)
#pragma unroll
      for (int r = 0; r < 4; ++r)
        ob[(size_t)r * DM + nt * 16] = acc[nt][r] * l_i[r];
  }
}

__global__ __launch_bounds__(256, 4) void attn_fwd(
    const void* __restrict__ qv, const void* __restrict__ kvv,
    void* __restrict__ outv, const int* __restrict__ flag)
{
  __shared__ ushort ks[BK * KPAD];           // kv tile, row-major padded (16.9KB)
  __shared__ ushort vs[BK * DM];             // granule-transposed V copy (16KB)
  __shared__ ushort ps[4 * 16 * PPAD];       // per-wave P staging (5KB)

  if (flag[0] != 0)  // block-uniform: barrier-safe
    attn_body<true >(qv, kvv, outv, ks, vs, ps);
  else
    attn_body<false>(qv, kvv, outv, ks, vs, ps);
}

extern "C" void kernel_launch(void* const* d_in, const int* in_sizes, int n_in,
                              void* d_out, int out_size, void* d_ws, size_t ws_size,
                              hipStream_t stream) {
  const void* q  = d_in[0];
  const void* kv = d_in[1];
  int* flag      = (int*)d_ws;

  detect_dtype<<<dim3(1), dim3(256), 0, stream>>>((const unsigned int*)q, flag);

  dim3 grid(NB, NQ / BQ);   // x=batch: a batch's 16 q-tile blocks share an XCD
  attn_fwd<<<grid, dim3(256), 0, stream>>>(q, kv, d_out, flag);
}